// Round 1
// baseline (1501.774 us; speedup 1.0000x reference)
//
#include <hip/hip_runtime.h>
#include <math.h>

#define S_TOT 2048
#define B_    64
#define E_    256
#define H_    256

typedef __fp16 half2v __attribute__((ext_vector_type(2)));

// Fused kernel: blocks [0, scan_blocks) run the sequential scan (one block per
// batch, 512 threads = 2 waves/SIMD for latency hiding); blocks
// [scan_blocks, grid) run the xp GEMM for the NEXT chunk. Kernel boundary =
// producer->consumer sync between chunks.
//
// launch_bounds (512,2): 8 waves = 2 waves/EU -> VGPR cap 256. Scan path needs
// ~105 live VGPRs (w=64 half2 + hk=16 + acc/addr) -> stays in arch VGPRs, no
// AGPR round-trips (the 256-thread version held 128 w regs and the compiler
// parked them in AGPRs: VGPR_Count was only 88).
__global__ __launch_bounds__(512, 2) void fused_step(
    const float* __restrict__ A,       // sentence chunk for gemm [Mc, E] (or null)
    const float* __restrict__ Wih,     // [E, H]
    const float* __restrict__ bias,    // [H]
    float*       __restrict__ xp_next, // [chunk*B, H] gemm output
    const float* __restrict__ xp_cur,  // [steps, B, H] scan input
    const float* __restrict__ Whh,     // [H, H]
    float*       __restrict__ h,       // [B, H] persistent state (= d_out)
    int steps, int scan_blocks)
{
    __shared__ float smem[32 * 68 + 32 * 64];   // gemm tiles; scan reuses front
    const int tid = threadIdx.x;

    if ((int)blockIdx.x < scan_blocks) {
        // ------------- scan: h_new = tanh(xp + h @ Whh), 512 threads ---------
        // thread (jg = tid>>3, ks = tid&7): outputs j0..j0+3 (j0 = jg*4),
        // k-range [ks*32, ks*32+32).  W slice = 64 half2 VGPRs; dot via
        // v_dot2_f32_f16 (f16 products exact in fp32, fp32 accumulate).
        // h ping-pong in LDS: 8 segments of 32 f16, stride 20 dwords ->
        // ks*20 mod 32 = {0,20,8,28,16,4,24,12}: conflict-free + 16B-aligned.
        float* hbuf = smem;              // [2][8][20] dwords
        const int b  = blockIdx.x;
        const int ks = tid & 7;
        const int jg = tid >> 3;         // 0..63
        const int j0 = jg << 2;
        // output index this lane holds after the split-butterfly reduction
        const int jf = j0 + ((ks & 1) << 1) + ((ks >> 1) & 1);

        // w[i][jj] = (Whh[ks*32+2i][j0+jj], Whh[ks*32+2i+1][j0+jj]) as f16x2
        half2v w[16][4];
        #pragma unroll
        for (int i = 0; i < 16; i++) {
            const float* r0 = &Whh[(size_t)(ks * 32 + 2 * i) * H_ + j0];
            const float* r1 = r0 + H_;
            #pragma unroll
            for (int jj = 0; jj < 4; jj++) {
                half2v v = __builtin_amdgcn_cvt_pkrtz(r0[jj], r1[jj]);
                int vi = __builtin_bit_cast(int, v);
                asm volatile("" : "+v"(vi));     // defeat load-sinking/remat
                w[i][jj] = __builtin_bit_cast(half2v, vi);
            }
        }

        if (tid < 128) {
            half2v hp = __builtin_amdgcn_cvt_pkrtz(h[b * H_ + 2 * tid],
                                                   h[b * H_ + 2 * tid + 1]);
            const int j = 2 * tid;
            ((half2v*)hbuf)[(j >> 5) * 20 + ((j & 31) >> 1)] = hp;
        }
        float xpn = xp_cur[(size_t)b * H_ + jf];
        __syncthreads();

        int p = 0;
        for (int s = 0; s < steps; s++) {
            const float xpc = xpn;
            if (s + 1 < steps)
                xpn = xp_cur[((size_t)(s + 1) * B_ + b) * H_ + jf];

            // this lane's 32-value h segment: 4 x ds_read_b128, conflict-free
            half2v hk[16];
            {
                const float4* hs = (const float4*)&hbuf[p * 160 + ks * 20];
                float4 t0 = hs[0], t1 = hs[1], t2 = hs[2], t3 = hs[3];
                *(float4*)&hk[0]  = t0;
                *(float4*)&hk[4]  = t1;
                *(float4*)&hk[8]  = t2;
                *(float4*)&hk[12] = t3;
            }

            float acc[4] = {0.f, 0.f, 0.f, 0.f};
            #pragma unroll
            for (int i = 0; i < 16; i++) {
                #pragma unroll
                for (int jj = 0; jj < 4; jj++)
                    acc[jj] = __builtin_amdgcn_fdot2(hk[i], w[i][jj],
                                                     acc[jj], false);
            }

            // split-butterfly reduce across the 8 ks lanes (lane bits 0..2);
            // rounds 1-2 split, round 3 duplicates (2 lanes share output jf).
            const bool b0 = (ks & 1), b1 = (ks & 2), b2 = (ks & 4);
            float r0, r1, q, v;
            {
                float s0 = b0 ? acc[0] : acc[2];
                float s1 = b0 ? acc[1] : acc[3];
                r0 = (b0 ? acc[2] : acc[0]) + __shfl_xor(s0, 1);
                r1 = (b0 ? acc[3] : acc[1]) + __shfl_xor(s1, 1);
            }
            {
                float s0 = b1 ? r0 : r1;
                q = (b1 ? r1 : r0) + __shfl_xor(s0, 2);
            }
            v = q + __shfl_xor(q, 4);

            v += xpc;
            const float e2 = __expf(2.f * v);
            const float hn = 1.f - 2.f / (e2 + 1.f);   // tanh(v)
            if (!b2) {
                ((__fp16*)hbuf)[(p ^ 1) * 320 + (jf >> 5) * 40 + (jf & 31)]
                    = (__fp16)hn;
                if (s == steps - 1) h[b * H_ + jf] = hn;   // fp32 carry-out
            }
            __syncthreads();
            p ^= 1;
        }
    } else if (A != nullptr) {
        // ---------------- gemm: xp_next = A @ Wih + bias (512 threads) -------
        float (*As)[68] = (float(*)[68])smem;
        float (*Bs)[64] = (float(*)[64])(smem + 32 * 68);

        const int gid = blockIdx.x - scan_blocks;
        const int bm = (gid >> 2) * 64;
        const int bn = (gid & 3) * 64;
        const int tx = tid & 15;         // 4 output cols
        const int ty = tid >> 4;         // 0..31 -> 2 output rows

        float acc[2][4] = {};

        const int ar = tid >> 3;         // 0..63
        const int ak = (tid & 7) << 2;   // 0..28
        const int br = tid >> 4;         // 0..31
        const int bc = (tid & 15) << 2;

        for (int k0 = 0; k0 < E_; k0 += 32) {
            float4 a0  = *(const float4*)&A[(size_t)(bm + ar) * E_ + k0 + ak];
            float4 bv0 = *(const float4*)&Wih[(size_t)(k0 + br) * H_ + bn + bc];

            As[ak+0][ar] = a0.x; As[ak+1][ar] = a0.y;
            As[ak+2][ar] = a0.z; As[ak+3][ar] = a0.w;
            *(float4*)&Bs[br][bc] = bv0;
            __syncthreads();

            #pragma unroll
            for (int kk = 0; kk < 32; kk++) {
                const float2 av = *(const float2*)&As[kk][ty << 1];
                const float4 bv = *(const float4*)&Bs[kk][tx << 2];
                acc[0][0] += av.x*bv.x; acc[0][1] += av.x*bv.y;
                acc[0][2] += av.x*bv.z; acc[0][3] += av.x*bv.w;
                acc[1][0] += av.y*bv.x; acc[1][1] += av.y*bv.y;
                acc[1][2] += av.y*bv.z; acc[1][3] += av.y*bv.w;
            }
            __syncthreads();
        }

        const float4 bb = *(const float4*)&bias[bn + (tx << 2)];
        #pragma unroll
        for (int i = 0; i < 2; i++) {
            float4 o;
            o.x = acc[i][0] + bb.x;
            o.y = acc[i][1] + bb.y;
            o.z = acc[i][2] + bb.z;
            o.w = acc[i][3] + bb.w;
            *(float4*)&xp_next[(size_t)(bm + (ty << 1) + i) * H_ + bn + (tx << 2)] = o;
        }
    }
}

extern "C" void kernel_launch(void* const* d_in, const int* in_sizes, int n_in,
                              void* d_out, int out_size, void* d_ws, size_t ws_size,
                              hipStream_t stream)
{
    const float* sentence = (const float*)d_in[0];  // [S,B,E]
    const float* h0       = (const float*)d_in[1];  // [B,H]
    const float* W_ih     = (const float*)d_in[2];  // [E,H]
    const float* W_hh     = (const float*)d_in[3];  // [H,H]
    const float* bias     = (const float*)d_in[4];  // [H]
    float* h  = (float*)d_out;
    float* ws = (float*)d_ws;

    // two ping-pong xp buffers, each [chunk*B, H]
    int chunk = 256;
    while ((size_t)2 * chunk * B_ * H_ * sizeof(float) > ws_size && chunk > 32)
        chunk >>= 1;
    const int nchunk = S_TOT / chunk;
    float* buf[2] = { ws, ws + (size_t)chunk * B_ * H_ };

    hipMemcpyAsync(h, h0, B_ * H_ * sizeof(float), hipMemcpyDeviceToDevice, stream);

    // pure gemm for chunk 0
    fused_step<<<chunk * 4, 512, 0, stream>>>(sentence, W_ih, bias, buf[0],
                                              nullptr, W_hh, h, 0, 0);
    for (int c = 0; c < nchunk; c++) {
        const bool last = (c == nchunk - 1);
        const int gemmb = last ? 0 : chunk * 4;
        const float* Anext = last ? nullptr
                                  : sentence + (size_t)(c + 1) * chunk * B_ * E_;
        fused_step<<<64 + gemmb, 512, 0, stream>>>(Anext, W_ih, bias,
                                                   buf[(c + 1) & 1],
                                                   buf[c & 1], W_hh, h,
                                                   chunk, 64);
    }
}

// Round 2
// 1323.825 us; speedup vs baseline: 1.1344x; 1.1344x over previous
//
#include <hip/hip_runtime.h>
#include <math.h>

#define S_TOT 2048
#define B_    64
#define E_    256
#define H_    256

typedef __fp16 half2v __attribute__((ext_vector_type(2)));

__device__ __forceinline__ float dpp_xor1(float x) {
    int i = __builtin_bit_cast(int, x);
    i = __builtin_amdgcn_mov_dpp(i, 0xB1, 0xF, 0xF, true);   // quad_perm [1,0,3,2]
    return __builtin_bit_cast(float, i);
}
__device__ __forceinline__ float dpp_xor2(float x) {
    int i = __builtin_bit_cast(int, x);
    i = __builtin_amdgcn_mov_dpp(i, 0x4E, 0xF, 0xF, true);   // quad_perm [2,3,0,1]
    return __builtin_bit_cast(float, i);
}

// Fused kernel: blocks [0, scan_blocks) run the sequential scan (one block per
// batch, 512 threads); blocks [scan_blocks, grid) run the xp GEMM for the NEXT
// chunk. Kernel boundary = producer->consumer sync between chunks.
//
// Scan split: ks = tid&3 (k-range of 64), jg = tid>>2 (outputs 2jg, 2jg+1).
// Cross-lane reduce = 2 rounds, masks 1 & 2 -> pure DPP quad_perm (VALU),
// no ds_swizzle on the serial critical path.
__global__ __launch_bounds__(512, 2) void fused_step(
    const float* __restrict__ A,       // sentence chunk for gemm [Mc, E] (or null)
    const float* __restrict__ Wih,     // [E, H]
    const float* __restrict__ bias,    // [H]
    float*       __restrict__ xp_next, // [chunk*B, H] gemm output
    const float* __restrict__ xp_cur,  // [steps, B, H] scan input
    const float* __restrict__ Whh,     // [H, H]
    float*       __restrict__ h,       // [B, H] persistent state (= d_out)
    int steps, int scan_blocks)
{
    __shared__ float smem[32 * 68 + 32 * 64];   // gemm tiles; scan reuses front
    const int tid = threadIdx.x;

    if ((int)blockIdx.x < scan_blocks) {
        // ------------- scan: h_new = tanh(xp + h @ Whh), 512 threads ---------
        // h ping-pong in LDS: 4 segments of 64 f16 (32 dwords) + 4-dword pad,
        // segment stride 36 dwords -> ks*36 mod 32 = {0,4,8,12}: the 4
        // broadcast groups of a wave read disjoint bank quads (conflict-free).
        float* hbuf = smem;              // [2][4][36] dwords
        const int b  = blockIdx.x;
        const int ks = tid & 3;          // k-range [ks*64, ks*64+64)
        const int jg = tid >> 2;         // 0..127 -> outputs 2jg, 2jg+1
        const int j0 = jg << 1;
        const int jf = j0 + (ks & 1);    // output this lane holds post-reduce

        // w[i][jj] = (Whh[ks*64+2i][j0+jj], Whh[ks*64+2i+1][j0+jj]) as f16x2
        half2v w[32][2];
        #pragma unroll
        for (int i = 0; i < 32; i++) {
            const float* r0 = &Whh[(size_t)(ks * 64 + 2 * i) * H_ + j0];
            const float* r1 = r0 + H_;
            #pragma unroll
            for (int jj = 0; jj < 2; jj++) {
                half2v v = __builtin_amdgcn_cvt_pkrtz(r0[jj], r1[jj]);
                int vi = __builtin_bit_cast(int, v);
                asm volatile("" : "+v"(vi));     // defeat load-sinking/remat
                w[i][jj] = __builtin_bit_cast(half2v, vi);
            }
        }

        if (tid < 128) {
            half2v hp = __builtin_amdgcn_cvt_pkrtz(h[b * H_ + 2 * tid],
                                                   h[b * H_ + 2 * tid + 1]);
            // j = 2*tid: segment tid>>5, dword offset tid&31
            ((half2v*)hbuf)[(tid >> 5) * 36 + (tid & 31)] = hp;
        }
        float xpn = xp_cur[(size_t)b * H_ + jf];
        __syncthreads();

        int p = 0;
        const int rd_base = ks * 36;                 // dwords
        const int wr_idx  = (jg >> 5) * 36 + (jg & 31);  // half2 slot (ks==0 lanes)
        for (int s = 0; s < steps; s++) {
            const float xpc = xpn;
            if (s + 1 < steps)
                xpn = xp_cur[((size_t)(s + 1) * B_ + b) * H_ + jf];

            // this lane's 64-value h segment: 8 x ds_read_b128 (broadcast x16)
            half2v hk[32];
            {
                const float4* hs = (const float4*)&hbuf[p * 144 + rd_base];
                #pragma unroll
                for (int t = 0; t < 8; t++)
                    *(float4*)&hk[t * 4] = hs[t];
            }

            // 64 fdot2, 4 partial chains of depth 16
            float p00 = 0.f, p01 = 0.f, p10 = 0.f, p11 = 0.f;
            #pragma unroll
            for (int i = 0; i < 16; i++) {
                p00 = __builtin_amdgcn_fdot2(hk[i], w[i][0], p00, false);
                p01 = __builtin_amdgcn_fdot2(hk[i], w[i][1], p01, false);
            }
            #pragma unroll
            for (int i = 16; i < 32; i++) {
                p10 = __builtin_amdgcn_fdot2(hk[i], w[i][0], p10, false);
                p11 = __builtin_amdgcn_fdot2(hk[i], w[i][1], p11, false);
            }
            const float acc0 = p00 + p10;            // partial(j0,   k-range ks)
            const float acc1 = p01 + p11;            // partial(j0+1, k-range ks)

            // split-butterfly over the 4 ks lanes, all DPP quad_perm:
            // round 1 (xor1): lane keeps one output, receives other k-half
            const bool b0 = (ks & 1);
            const float r = (b0 ? acc1 : acc0) + dpp_xor1(b0 ? acc0 : acc1);
            // round 2 (xor2): combine remaining k-halves (result duplicated
            // across the xor-2 pair)
            const float v = r + dpp_xor2(r) + xpc;

            const float e2 = __expf(2.f * v);
            const float hn = 1.f - 2.f / (e2 + 1.f);   // tanh(v)

            // pack (j0, j0+1) into one half2; single writer per quad (ks==0)
            const float other = dpp_xor1(hn);
            if (ks == 0) {
                ((half2v*)hbuf)[(p ^ 1) * 144 + wr_idx] =
                    __builtin_amdgcn_cvt_pkrtz(hn, other);
                if (s == steps - 1) {                  // fp32 carry-out
                    float2 o; o.x = hn; o.y = other;
                    *(float2*)&h[b * H_ + j0] = o;
                }
            }
            __syncthreads();
            p ^= 1;
        }
    } else if (A != nullptr) {
        // ---------------- gemm: xp_next = A @ Wih + bias (512 threads) -------
        float (*As)[68] = (float(*)[68])smem;
        float (*Bs)[64] = (float(*)[64])(smem + 32 * 68);

        const int gid = blockIdx.x - scan_blocks;
        const int bm = (gid >> 2) * 64;
        const int bn = (gid & 3) * 64;
        const int tx = tid & 15;         // 4 output cols
        const int ty = tid >> 4;         // 0..31 -> 2 output rows

        float acc[2][4] = {};

        const int ar = tid >> 3;         // 0..63
        const int ak = (tid & 7) << 2;   // 0..28
        const int br = tid >> 4;         // 0..31
        const int bc = (tid & 15) << 2;

        for (int k0 = 0; k0 < E_; k0 += 32) {
            float4 a0  = *(const float4*)&A[(size_t)(bm + ar) * E_ + k0 + ak];
            float4 bv0 = *(const float4*)&Wih[(size_t)(k0 + br) * H_ + bn + bc];

            As[ak+0][ar] = a0.x; As[ak+1][ar] = a0.y;
            As[ak+2][ar] = a0.z; As[ak+3][ar] = a0.w;
            *(float4*)&Bs[br][bc] = bv0;
            __syncthreads();

            #pragma unroll
            for (int kk = 0; kk < 32; kk++) {
                const float2 av = *(const float2*)&As[kk][ty << 1];
                const float4 bv = *(const float4*)&Bs[kk][tx << 2];
                acc[0][0] += av.x*bv.x; acc[0][1] += av.x*bv.y;
                acc[0][2] += av.x*bv.z; acc[0][3] += av.x*bv.w;
                acc[1][0] += av.y*bv.x; acc[1][1] += av.y*bv.y;
                acc[1][2] += av.y*bv.z; acc[1][3] += av.y*bv.w;
            }
            __syncthreads();
        }

        const float4 bb = *(const float4*)&bias[bn + (tx << 2)];
        #pragma unroll
        for (int i = 0; i < 2; i++) {
            float4 o;
            o.x = acc[i][0] + bb.x;
            o.y = acc[i][1] + bb.y;
            o.z = acc[i][2] + bb.z;
            o.w = acc[i][3] + bb.w;
            *(float4*)&xp_next[(size_t)(bm + (ty << 1) + i) * H_ + bn + (tx << 2)] = o;
        }
    }
}

extern "C" void kernel_launch(void* const* d_in, const int* in_sizes, int n_in,
                              void* d_out, int out_size, void* d_ws, size_t ws_size,
                              hipStream_t stream)
{
    const float* sentence = (const float*)d_in[0];  // [S,B,E]
    const float* h0       = (const float*)d_in[1];  // [B,H]
    const float* W_ih     = (const float*)d_in[2];  // [E,H]
    const float* W_hh     = (const float*)d_in[3];  // [H,H]
    const float* bias     = (const float*)d_in[4];  // [H]
    float* h  = (float*)d_out;
    float* ws = (float*)d_ws;

    // two ping-pong xp buffers, each [chunk*B, H]
    int chunk = 256;
    while ((size_t)2 * chunk * B_ * H_ * sizeof(float) > ws_size && chunk > 32)
        chunk >>= 1;
    const int nchunk = S_TOT / chunk;
    float* buf[2] = { ws, ws + (size_t)chunk * B_ * H_ };

    hipMemcpyAsync(h, h0, B_ * H_ * sizeof(float), hipMemcpyDeviceToDevice, stream);

    // pure gemm for chunk 0
    fused_step<<<chunk * 4, 512, 0, stream>>>(sentence, W_ih, bias, buf[0],
                                              nullptr, W_hh, h, 0, 0);
    for (int c = 0; c < nchunk; c++) {
        const bool last = (c == nchunk - 1);
        const int gemmb = last ? 0 : chunk * 4;
        const float* Anext = last ? nullptr
                                  : sentence + (size_t)(c + 1) * chunk * B_ * E_;
        fused_step<<<64 + gemmb, 512, 0, stream>>>(Anext, W_ih, bias,
                                                   buf[(c + 1) & 1],
                                                   buf[c & 1], W_hh, h,
                                                   chunk, 64);
    }
}